// Round 7
// baseline (431.757 us; speedup 1.0000x reference)
//
#include <hip/hip_runtime.h>
#include <math.h>

#define B_   256
#define S_   200
#define NQ_  400
#define K_   4
#define M_   50
#define KD_  50
#define VD_  200
#define FD_  50
#define T_   (B_*S_)   // 51200 tokens

// ---------------------------------------------------------------------------
// Kernel 1: per-token embeddings + correlation softmax. One wave per token.
// ---------------------------------------------------------------------------
__global__ __launch_bounds__(256) void k1_embed(
    const int* __restrict__ q_data, const int* __restrict__ r_data,
    const float* __restrict__ q_tab, const float* __restrict__ key_mem,
    const float* __restrict__ W_qk, const float* __restrict__ b_qk,
    const float* __restrict__ W_v3, const float* __restrict__ b_v,
    float* __restrict__ V, float* __restrict__ corr)
{
    const int wave = threadIdx.x >> 6;
    const int lane = threadIdx.x & 63;
    const int tok  = blockIdx.x * 4 + wave;

    const int q = q_data[tok];
    const int r = r_data[tok];
    const float qmask = (q > 0) ? 1.0f : 0.0f;
    int idx = q - 1;
    if (idx < 0) idx = 0;
    if (idx > NQ_ - 1) idx = NQ_ - 1;

    float wc[K_];
#pragma unroll
    for (int k = 0; k < K_; ++k) {
        float dist = fabsf((float)k - (float)r) / (float)(K_ - 1);
        float w = 1.0f - dist;
        wc[k] = (w > 0.0f) ? w : 0.0f;
    }

    for (int j = lane; j < VD_; j += 64) {
        float s = 0.0f;
#pragma unroll
        for (int k = 0; k < K_; ++k)
            s += wc[k] * W_v3[((size_t)k * NQ_ + idx) * VD_ + j];
        V[(size_t)tok * VD_ + j] = b_v[j] + qmask * s;
    }

    __shared__ float sqk[4][KD_];
    const float* qe = q_tab + (size_t)q * KD_;
    if (lane < KD_) {
        float acc = b_qk[lane];
#pragma unroll 10
        for (int k = 0; k < KD_; ++k)
            acc += qe[k] * W_qk[k * KD_ + lane];
        sqk[wave][lane] = tanhf(acc);
    }
    __syncthreads();

    float c = -INFINITY;
    if (lane < M_) {
        float acc = 0.0f;
#pragma unroll 10
        for (int k = 0; k < KD_; ++k)
            acc += sqk[wave][k] * key_mem[lane * KD_ + k];
        c = acc;
    }
    float mx = c;
#pragma unroll
    for (int off = 32; off; off >>= 1) mx = fmaxf(mx, __shfl_xor(mx, off));
    float e = (lane < M_) ? expf(c - mx) : 0.0f;
    float sm = e;
#pragma unroll
    for (int off = 32; off; off >>= 1) sm += __shfl_xor(sm, off);
    if (lane < M_) corr[(size_t)tok * M_ + lane] = e / sm;
}

// ---------------------------------------------------------------------------
// Kernel 2 v4: dual GEMM, double-buffered LDS, ONE barrier per K-tile.
// BKT=8, LDS 28.2KB (5 blocks/CU = grid's 5 blocks/CU). Per tile: issue
// next-tile global loads -> compute cur buffer -> ds_write nxt -> barrier.
// WAR safe: __syncthreads drains prior tile's LDS reads (lgkmcnt 0).
// ---------------------------------------------------------------------------
#define BT2 40
#define BKT 8
#define NT2 (VD_ / BKT)   // 25
__global__ __launch_bounds__(256) void k2_gemm(
    const float* __restrict__ V,
    const float* __restrict__ W_e, const float* __restrict__ b_e,
    const float* __restrict__ W_a, const float* __restrict__ b_a,
    float* __restrict__ erase, float* __restrict__ add)
{
    __shared__ float sWe[2][BKT][VD_];   // 12.8 KB
    __shared__ float sWa[2][BKT][VD_];   // 12.8 KB
    __shared__ float sVt[2][BKT][BT2];   // 2.56 KB

    const int tid = threadIdx.x;
    const int ty  = tid / 50;
    const int tx  = tid % 50;
    const bool act = (tid < 250);
    const int tok0 = blockIdx.x * BT2;
    const int c  = tx * 4;
    const int t0 = ty * 8;

    // staging: W = 400 float4/matrix/tile -> tid<200 handles rows wr, wr+4
    const bool wstage = (tid < 200);
    const int wr  = tid / 50;            // 0..3
    const int wc4 = (tid % 50) * 4;
    // V = 320 floats/tile -> tid<160 handles kk rows vk, vk+4
    const bool vstage = (tid < 160);
    const int vk = tid / 40;             // 0..3
    const int vt = tid % 40;

    float accE[8][4], accA[8][4];
#pragma unroll
    for (int i = 0; i < 8; ++i)
#pragma unroll
        for (int l = 0; l < 4; ++l) { accE[i][l] = 0.f; accA[i][l] = 0.f; }

    float4 rWe0, rWe1, rWa0, rWa1;
    float  rV0 = 0.f, rV1 = 0.f;

    // ---- stage tile 0 into buffer 0 ----
    if (wstage) {
        rWe0 = *(const float4*)&W_e[wr * VD_ + wc4];
        rWe1 = *(const float4*)&W_e[(wr + 4) * VD_ + wc4];
        rWa0 = *(const float4*)&W_a[wr * VD_ + wc4];
        rWa1 = *(const float4*)&W_a[(wr + 4) * VD_ + wc4];
    }
    if (vstage) {
        rV0 = V[(size_t)(tok0 + vt) * VD_ + vk];
        rV1 = V[(size_t)(tok0 + vt) * VD_ + vk + 4];
    }
    if (wstage) {
        *(float4*)&sWe[0][wr][wc4]     = rWe0;
        *(float4*)&sWe[0][wr + 4][wc4] = rWe1;
        *(float4*)&sWa[0][wr][wc4]     = rWa0;
        *(float4*)&sWa[0][wr + 4][wc4] = rWa1;
    }
    if (vstage) {
        sVt[0][vk][vt]     = rV0;
        sVt[0][vk + 4][vt] = rV1;
    }
    __syncthreads();

    for (int t = 0; t < NT2; ++t) {
        const int cur = t & 1, nxt = cur ^ 1;
        const int ktn = (t + 1) * BKT;
        if (t + 1 < NT2) {
            if (wstage) {
                rWe0 = *(const float4*)&W_e[(ktn + wr) * VD_ + wc4];
                rWe1 = *(const float4*)&W_e[(ktn + wr + 4) * VD_ + wc4];
                rWa0 = *(const float4*)&W_a[(ktn + wr) * VD_ + wc4];
                rWa1 = *(const float4*)&W_a[(ktn + wr + 4) * VD_ + wc4];
            }
            if (vstage) {
                rV0 = V[(size_t)(tok0 + vt) * VD_ + ktn + vk];
                rV1 = V[(size_t)(tok0 + vt) * VD_ + ktn + vk + 4];
            }
        }

        if (act) {
#pragma unroll
            for (int kk = 0; kk < BKT; ++kk) {
                float4 we = *(const float4*)&sWe[cur][kk][c];
                float4 wa = *(const float4*)&sWa[cur][kk][c];
                float4 v0 = *(const float4*)&sVt[cur][kk][t0];
                float4 v1 = *(const float4*)&sVt[cur][kk][t0 + 4];
                float vv[8] = {v0.x, v0.y, v0.z, v0.w, v1.x, v1.y, v1.z, v1.w};
#pragma unroll
                for (int i = 0; i < 8; ++i) {
                    accE[i][0] = fmaf(vv[i], we.x, accE[i][0]);
                    accE[i][1] = fmaf(vv[i], we.y, accE[i][1]);
                    accE[i][2] = fmaf(vv[i], we.z, accE[i][2]);
                    accE[i][3] = fmaf(vv[i], we.w, accE[i][3]);
                    accA[i][0] = fmaf(vv[i], wa.x, accA[i][0]);
                    accA[i][1] = fmaf(vv[i], wa.y, accA[i][1]);
                    accA[i][2] = fmaf(vv[i], wa.z, accA[i][2]);
                    accA[i][3] = fmaf(vv[i], wa.w, accA[i][3]);
                }
            }
        }

        if (t + 1 < NT2) {
            if (wstage) {
                *(float4*)&sWe[nxt][wr][wc4]     = rWe0;
                *(float4*)&sWe[nxt][wr + 4][wc4] = rWe1;
                *(float4*)&sWa[nxt][wr][wc4]     = rWa0;
                *(float4*)&sWa[nxt][wr + 4][wc4] = rWa1;
            }
            if (vstage) {
                sVt[nxt][vk][vt]     = rV0;
                sVt[nxt][vk + 4][vt] = rV1;
            }
            __syncthreads();
        }
    }

    if (act) {
        const float4 be = *(const float4*)&b_e[c];
        const float4 ba = *(const float4*)&b_a[c];
#pragma unroll
        for (int i = 0; i < 8; ++i) {
            const size_t tok = tok0 + t0 + i;
            float4 eo, ao;
            eo.x = 1.0f / (1.0f + expf(-(accE[i][0] + be.x)));
            eo.y = 1.0f / (1.0f + expf(-(accE[i][1] + be.y)));
            eo.z = 1.0f / (1.0f + expf(-(accE[i][2] + be.z)));
            eo.w = 1.0f / (1.0f + expf(-(accE[i][3] + be.w)));
            ao.x = tanhf(accA[i][0] + ba.x);
            ao.y = tanhf(accA[i][1] + ba.y);
            ao.z = tanhf(accA[i][2] + ba.z);
            ao.w = tanhf(accA[i][3] + ba.w);
            *(float4*)&erase[tok * VD_ + c] = eo;
            *(float4*)&add[tok * VD_ + c]   = ao;
        }
    }
}

// ---------------------------------------------------------------------------
// Kernel 3 v4: scan with M split across 2 groups. 512-thread blocks:
// thread (j = tid&255, g = tid>>8) owns slots g*25..g*25+24 of column j.
// Doubles TLP (2 waves/SIMD) and halves per-thread issue + r-chain depth.
// Partial r exchanged via double-buffered rpart (g1 writes, g0 adds+stores).
// Keeps 4-deep e/a register pipeline + corr 4-ring LDS staging.
// ---------------------------------------------------------------------------
__global__ __launch_bounds__(512) void k3_scan(
    const float* __restrict__ init_mem,
    const float* __restrict__ corr, const float* __restrict__ erase,
    const float* __restrict__ add, float* __restrict__ reads)
{
    const int b   = blockIdx.x;
    const int tid = threadIdx.x;
    const int j   = tid & 255;
    const int g   = tid >> 8;          // 0 or 1
    const bool act = (j < VD_);
    const int m0  = g * 25;

    float mem[25];
    if (act) {
#pragma unroll
        for (int m = 0; m < 25; ++m) mem[m] = init_mem[(m0 + m) * VD_ + j];
    }

    __shared__ float wsh[4][M_];
    __shared__ float rpart[2][256];

    const float* cb = corr  + (size_t)b * S_ * M_;
    const float* eb = erase + (size_t)b * S_ * VD_;
    const float* ab = add   + (size_t)b * S_ * VD_;
    float* rb       = reads + (size_t)b * S_ * VD_;

    float e0=0,a0=0,e1=0,a1=0,e2=0,a2=0,e3=0,a3=0;
    if (act) {
        e0 = eb[0*VD_+j]; a0 = ab[0*VD_+j];
        e1 = eb[1*VD_+j]; a1 = ab[1*VD_+j];
        e2 = eb[2*VD_+j]; a2 = ab[2*VD_+j];
        e3 = eb[3*VD_+j]; a3 = ab[3*VD_+j];
    }
    float wcA = 0.f, wcB = 0.f;
    if (tid < M_) {
        wsh[0][tid] = cb[0*M_+tid];
        wsh[1][tid] = cb[1*M_+tid];
        wcA = cb[2*M_+tid];
        wcB = cb[3*M_+tid];
    }
    __syncthreads();

    for (int s = 0; s < S_; s += 2) {
        if (tid < M_ && s + 2 < S_) {
            wsh[(s+2)&3][tid] = wcA;
            wsh[(s+3)&3][tid] = wcB;
        }
        float e4=0,a4=0,e5=0,a5=0, wcC=0.f, wcD=0.f;
        if (act && s+4 < S_) { e4 = eb[(s+4)*VD_+j]; a4 = ab[(s+4)*VD_+j]; }
        if (act && s+5 < S_) { e5 = eb[(s+5)*VD_+j]; a5 = ab[(s+5)*VD_+j]; }
        if (tid < M_ && s+4 < S_) wcC = cb[(s+4)*M_+tid];
        if (tid < M_ && s+5 < S_) wcD = cb[(s+5)*M_+tid];

        // step s (rpart buffer 0)
        {
            const float* w = &wsh[s & 3][m0];
            float r = 0.f;
#pragma unroll
            for (int m = 0; m < 25; ++m) {
                float wm = w[m];
                r = fmaf(wm, mem[m], r);
                float t = fmaf(-e0, mem[m], a0);
                mem[m] = fmaf(wm, t, mem[m]);
            }
            if (g == 1 && act) rpart[0][j] = r;
            __syncthreads();
            if (g == 0 && act) rb[s * VD_ + j] = r + rpart[0][j];
        }
        // step s+1 (rpart buffer 1)
        {
            const float* w = &wsh[(s+1) & 3][m0];
            float r = 0.f;
#pragma unroll
            for (int m = 0; m < 25; ++m) {
                float wm = w[m];
                r = fmaf(wm, mem[m], r);
                float t = fmaf(-e1, mem[m], a1);
                mem[m] = fmaf(wm, t, mem[m]);
            }
            if (g == 1 && act) rpart[1][j] = r;
            __syncthreads();
            if (g == 0 && act) rb[(s+1) * VD_ + j] = r + rpart[1][j];
        }
        e0 = e2; a0 = a2; e1 = e3; a1 = a3;
        e2 = e4; a2 = a4; e3 = e5; a3 = a5;
        wcA = wcC; wcB = wcD;
    }
}

// ---------------------------------------------------------------------------
// Kernel 4: summary GEMM + fused head (unchanged).
// ---------------------------------------------------------------------------
#define BT4 80
#define KA  250
#define BK4 25
__global__ __launch_bounds__(256) void k4_head(
    const int* __restrict__ q_data, const float* __restrict__ q_tab,
    const float* __restrict__ reads,
    const float* __restrict__ W_sum, const float* __restrict__ b_sum,
    const float* __restrict__ W_ab, const float* __restrict__ b_ab,
    const float* __restrict__ W_th, const float* __restrict__ b_th,
    const float* __restrict__ W_disc, const float* __restrict__ b_disc,
    float* __restrict__ out)
{
    __shared__ __align__(16) float sAt[BK4][84];
    __shared__ __align__(16) float sW[BK4][52];
    __shared__ __align__(16) float sSum[BT4][52];
    __shared__ int sQ[BT4];

    const int tid  = threadIdx.x;
    const int tok0 = blockIdx.x * BT4;

    const int ty = tid / 25;
    const int tx = tid % 25;
    const bool act = (tid < 250);
    const int t0 = ty * 8;

    if (tid < BT4) sQ[tid] = q_data[tok0 + tid];

    float acc[8][2];
#pragma unroll
    for (int i = 0; i < 8; ++i) { acc[i][0] = 0.f; acc[i][1] = 0.f; }

    for (int kt = 0; kt < KA; kt += BK4) {
        __syncthreads();
        for (int i = tid; i < BT4 * BK4; i += 256) {
            int t = i / BK4, kk = i % BK4;
            float v;
            if (kt < VD_) v = reads[(size_t)(tok0 + t) * VD_ + kt + kk];
            else          v = q_tab[(size_t)sQ[t] * KD_ + (kt - VD_) + kk];
            sAt[kk][t] = v;
        }
        for (int i = tid; i < BK4 * FD_; i += 256) {
            int kk = i / FD_, col = i % FD_;
            sW[kk][col] = W_sum[(size_t)(kt + kk) * FD_ + col];
        }
        __syncthreads();

        if (act) {
#pragma unroll 5
            for (int kk = 0; kk < BK4; ++kk) {
                float2 w = *(const float2*)&sW[kk][2 * tx];
                float4 a0 = *(const float4*)&sAt[kk][t0];
                float4 a1 = *(const float4*)&sAt[kk][t0 + 4];
                float av[8] = {a0.x, a0.y, a0.z, a0.w, a1.x, a1.y, a1.z, a1.w};
#pragma unroll
                for (int i = 0; i < 8; ++i) {
                    acc[i][0] += av[i] * w.x;
                    acc[i][1] += av[i] * w.y;
                }
            }
        }
    }

    if (act) {
        const float b0 = b_sum[2 * tx], b1 = b_sum[2 * tx + 1];
#pragma unroll
        for (int i = 0; i < 8; ++i) {
            sSum[t0 + i][2 * tx]     = tanhf(acc[i][0] + b0);
            sSum[t0 + i][2 * tx + 1] = tanhf(acc[i][1] + b1);
        }
    }
    __syncthreads();

    const int wv   = tid >> 6;
    const int lane = tid & 63;
    for (int lt = wv * 20; lt < wv * 20 + 20; ++lt) {
        const int tok = tok0 + lt;
        const float s  = (lane < FD_) ? sSum[lt][lane] : 0.0f;
        const int  qi  = sQ[lt];
        const float qv = (lane < KD_) ? q_tab[(size_t)qi * KD_ + lane] : 0.0f;

        float v_ab = (lane < FD_) ? s * W_ab[lane] : 0.0f;
        float v_d  = ((lane < FD_) ? s * W_disc[lane] : 0.0f)
                   + ((lane < KD_) ? qv * W_disc[FD_ + lane] : 0.0f);
        float v_t0 = (lane < KD_) ? qv * W_th[lane * 3 + 0] : 0.0f;
        float v_t1 = (lane < KD_) ? qv * W_th[lane * 3 + 1] : 0.0f;
        float v_t2 = (lane < KD_) ? qv * W_th[lane * 3 + 2] : 0.0f;

#pragma unroll
        for (int off = 32; off; off >>= 1) {
            v_ab += __shfl_xor(v_ab, off);
            v_d  += __shfl_xor(v_d,  off);
            v_t0 += __shfl_xor(v_t0, off);
            v_t1 += __shfl_xor(v_t1, off);
            v_t2 += __shfl_xor(v_t2, off);
        }

        if (lane == 0) {
            float theta = 3.0f * (v_ab + b_ab[0]);
            float xd = v_d + b_disc[0];
            float alpha = fmaxf(xd, 0.0f) + log1pf(expf(-fabsf(xd)));
            float beta0 = tanhf(v_t0 + b_th[0]);
            float beta1 = tanhf(v_t1 + b_th[1]);
            float beta2 = tanhf(v_t2 + b_th[2]);
            float c1 = alpha * (theta - beta0);
            float c2 = c1 + alpha * (theta - beta1);
            float c3 = c2 + alpha * (theta - beta2);
            float mx = fmaxf(fmaxf(0.0f, c1), fmaxf(c2, c3));
            float e0 = expf(0.0f - mx), e1 = expf(c1 - mx),
                  e2 = expf(c2 - mx), e3 = expf(c3 - mx);
            float s4 = e0 + e1 + e2 + e3;
            float4 o = make_float4(e0 / s4, e1 / s4, e2 / s4, e3 / s4);
            *(float4*)&out[(size_t)tok * 4] = o;
        }
    }
}

// ---------------------------------------------------------------------------
extern "C" void kernel_launch(void* const* d_in, const int* in_sizes, int n_in,
                              void* d_out, int out_size, void* d_ws, size_t ws_size,
                              hipStream_t stream) {
    const int*   q_data   = (const int*)  d_in[0];
    const int*   r_data   = (const int*)  d_in[1];
    const float* q_tab    = (const float*)d_in[2];
    const float* key_mem  = (const float*)d_in[3];
    const float* init_mem = (const float*)d_in[4];
    const float* W_qk     = (const float*)d_in[5];
    const float* b_qk     = (const float*)d_in[6];
    const float* W_v3     = (const float*)d_in[7];
    const float* b_v      = (const float*)d_in[8];
    const float* W_e      = (const float*)d_in[9];
    const float* b_e      = (const float*)d_in[10];
    const float* W_a      = (const float*)d_in[11];
    const float* b_a      = (const float*)d_in[12];
    const float* W_sum    = (const float*)d_in[13];
    const float* b_sum    = (const float*)d_in[14];
    const float* W_ab     = (const float*)d_in[15];
    const float* b_ab     = (const float*)d_in[16];
    const float* W_th     = (const float*)d_in[17];
    const float* b_th     = (const float*)d_in[18];
    const float* W_disc   = (const float*)d_in[19];
    const float* b_disc   = (const float*)d_in[20];

    float* ws    = (float*)d_ws;
    float* V     = ws;                       // T*VD
    float* reads = ws;                       // aliases V (V dead after k2)
    float* corr  = ws + (size_t)T_ * VD_;    // T*M
    float* erase = corr + (size_t)T_ * M_;   // T*VD
    float* add   = erase + (size_t)T_ * VD_; // T*VD

    k1_embed<<<T_ / 4, 256, 0, stream>>>(q_data, r_data, q_tab, key_mem,
                                         W_qk, b_qk, W_v3, b_v, V, corr);
    k2_gemm<<<T_ / BT2, 256, 0, stream>>>(V, W_e, b_e, W_a, b_a, erase, add);
    k3_scan<<<B_, 512, 0, stream>>>(init_mem, corr, erase, add, reads);
    k4_head<<<T_ / BT4, 256, 0, stream>>>(q_data, q_tab, reads,
                                          W_sum, b_sum, W_ab, b_ab,
                                          W_th, b_th, W_disc, b_disc,
                                          (float*)d_out);
}

// Round 8
// 252.992 us; speedup vs baseline: 1.7066x; 1.7066x over previous
//
#include <hip/hip_runtime.h>
#include <math.h>

#define B_   256
#define S_   200
#define NQ_  400
#define K_   4
#define M_   50
#define KD_  50
#define VD_  200
#define FD_  50
#define T_   (B_*S_)   // 51200 tokens
#define NE_  ((NQ_+1)*K_)   // 1604 distinct (q,r) rows

// ---------------------------------------------------------------------------
// kA1: corr LUT [401][50]. corr is a pure function of q.
// One wave per q value; 4 waves/block.
// ---------------------------------------------------------------------------
__global__ __launch_bounds__(256) void kA1_corrlut(
    const float* __restrict__ q_tab, const float* __restrict__ key_mem,
    const float* __restrict__ W_qk, const float* __restrict__ b_qk,
    float* __restrict__ clut)
{
    const int wave = threadIdx.x >> 6;
    const int lane = threadIdx.x & 63;
    int qi = blockIdx.x * 4 + wave;
    const bool valid = (qi <= NQ_);
    if (qi > NQ_) qi = NQ_;

    __shared__ float sqk[4][KD_];
    const float* qe = q_tab + (size_t)qi * KD_;
    if (lane < KD_) {
        float acc = b_qk[lane];
#pragma unroll 10
        for (int k = 0; k < KD_; ++k)
            acc += qe[k] * W_qk[k * KD_ + lane];
        sqk[wave][lane] = tanhf(acc);
    }
    __syncthreads();

    float c = -INFINITY;
    if (lane < M_) {
        float acc = 0.0f;
#pragma unroll 10
        for (int k = 0; k < KD_; ++k)
            acc += sqk[wave][k] * key_mem[lane * KD_ + k];
        c = acc;
    }
    float mx = c;
#pragma unroll
    for (int off = 32; off; off >>= 1) mx = fmaxf(mx, __shfl_xor(mx, off));
    float e = (lane < M_) ? expf(c - mx) : 0.0f;
    float sm = e;
#pragma unroll
    for (int off = 32; off; off >>= 1) sm += __shfl_xor(sm, off);
    if (valid && lane < M_) clut[(size_t)qi * M_ + lane] = e / sm;
}

// ---------------------------------------------------------------------------
// kA2: erase/add LUT [1604][200]. erase/add are pure functions of (q,r).
// One block per q: stage the 4 value_emb rows (r=0..3) as sV[k][r] (float4
// broadcast-friendly), then thread c computes the K=200 dual dot for its
// column across all 4 r-variants. 0.26 GFLOP total (32x less than per-token).
// ---------------------------------------------------------------------------
__global__ __launch_bounds__(256) void kA2_ealut(
    const float* __restrict__ W_v3, const float* __restrict__ b_v,
    const float* __restrict__ W_e, const float* __restrict__ b_e,
    const float* __restrict__ W_a, const float* __restrict__ b_a,
    float* __restrict__ elut, float* __restrict__ alut)
{
    __shared__ __align__(16) float sV[VD_][4];   // [k][r]
    const int qi  = blockIdx.x;                  // 0..400
    const int tid = threadIdx.x;
    const float qm = (qi > 0) ? 1.0f : 0.0f;
    int idx = qi - 1;
    if (idx < 0) idx = 0;

    // wc[r][k] = clip(1 - |k-r|/(K-1), 0), exactly as reference
    float wc[4][4];
#pragma unroll
    for (int r = 0; r < 4; ++r)
#pragma unroll
        for (int k = 0; k < 4; ++k) {
            float dist = fabsf((float)k - (float)r) / (float)(K_ - 1);
            float w = 1.0f - dist;
            wc[r][k] = (w > 0.0f) ? w : 0.0f;
        }

    if (tid < VD_) {
        float w3[4];
#pragma unroll
        for (int k = 0; k < 4; ++k)
            w3[k] = W_v3[((size_t)k * NQ_ + idx) * VD_ + tid];
        float bv = b_v[tid];
#pragma unroll
        for (int r = 0; r < 4; ++r) {
            float s = wc[r][0]*w3[0] + wc[r][1]*w3[1] + wc[r][2]*w3[2] + wc[r][3]*w3[3];
            sV[tid][r] = bv + qm * s;
        }
    }
    __syncthreads();

    if (tid < VD_) {
        const int c = tid;
        float accE[4] = {0.f,0.f,0.f,0.f}, accA[4] = {0.f,0.f,0.f,0.f};
#pragma unroll 4
        for (int k = 0; k < VD_; ++k) {
            float we = W_e[(size_t)k * VD_ + c];
            float wa = W_a[(size_t)k * VD_ + c];
            float4 v = *(const float4*)&sV[k][0];
            float vv[4] = {v.x, v.y, v.z, v.w};
#pragma unroll
            for (int r = 0; r < 4; ++r) {
                accE[r] = fmaf(vv[r], we, accE[r]);
                accA[r] = fmaf(vv[r], wa, accA[r]);
            }
        }
        const float be = b_e[c], ba = b_a[c];
#pragma unroll
        for (int r = 0; r < 4; ++r) {
            const size_t row = (size_t)qi * K_ + r;
            elut[row * VD_ + c] = 1.0f / (1.0f + expf(-(accE[r] + be)));
            alut[row * VD_ + c] = tanhf(accA[r] + ba);
        }
    }
}

// ---------------------------------------------------------------------------
// kB: sequential scan, M split across 2 groups (512 threads), LUT-fed.
// e/a rows come from elut/alut[eid = q*4+r] (L2-resident, 2.6 MB), corr rows
// from clut[q]. q/r for the batch staged once in LDS. 4-deep e/a register
// pipeline + 4-ring corr LDS staging as before.
// ---------------------------------------------------------------------------
__global__ __launch_bounds__(512) void kB_scan(
    const int* __restrict__ q_data, const int* __restrict__ r_data,
    const float* __restrict__ init_mem, const float* __restrict__ clut,
    const float* __restrict__ elut, const float* __restrict__ alut,
    float* __restrict__ reads)
{
    const int b   = blockIdx.x;
    const int tid = threadIdx.x;
    const int j   = tid & 255;
    const int g   = tid >> 8;          // 0 or 1
    const bool act = (j < VD_);
    const int m0  = g * 25;

    __shared__ int   sQ[S_], sR[S_];
    __shared__ float wsh[4][M_];
    __shared__ float rpart[2][256];

    for (int i = tid; i < S_; i += 512) {
        sQ[i] = q_data[b * S_ + i];
        sR[i] = r_data[b * S_ + i];
    }

    float mem[25];
    if (act) {
#pragma unroll
        for (int m = 0; m < 25; ++m) mem[m] = init_mem[(m0 + m) * VD_ + j];
    }
    __syncthreads();   // sQ/sR visible

    float* rb = reads + (size_t)b * S_ * VD_;

    // prologue: e/a rows 0..3 in regs; corr rows 0,1 in LDS; 2,3 in regs
    float e0=0,a0=0,e1=0,a1=0,e2=0,a2=0,e3=0,a3=0;
    if (act) {
        size_t i0 = (size_t)(sQ[0]*K_ + sR[0]) * VD_ + j;
        size_t i1 = (size_t)(sQ[1]*K_ + sR[1]) * VD_ + j;
        size_t i2 = (size_t)(sQ[2]*K_ + sR[2]) * VD_ + j;
        size_t i3 = (size_t)(sQ[3]*K_ + sR[3]) * VD_ + j;
        e0 = elut[i0]; a0 = alut[i0];
        e1 = elut[i1]; a1 = alut[i1];
        e2 = elut[i2]; a2 = alut[i2];
        e3 = elut[i3]; a3 = alut[i3];
    }
    float wcA = 0.f, wcB = 0.f;
    if (tid < M_) {
        wsh[0][tid] = clut[(size_t)sQ[0] * M_ + tid];
        wsh[1][tid] = clut[(size_t)sQ[1] * M_ + tid];
        wcA = clut[(size_t)sQ[2] * M_ + tid];
        wcB = clut[(size_t)sQ[3] * M_ + tid];
    }
    __syncthreads();

    for (int s = 0; s < S_; s += 2) {
        if (tid < M_ && s + 2 < S_) {
            wsh[(s+2)&3][tid] = wcA;
            wsh[(s+3)&3][tid] = wcB;
        }
        float e4=0,a4=0,e5=0,a5=0, wcC=0.f, wcD=0.f;
        if (act && s+4 < S_) {
            size_t i4 = (size_t)(sQ[s+4]*K_ + sR[s+4]) * VD_ + j;
            e4 = elut[i4]; a4 = alut[i4];
        }
        if (act && s+5 < S_) {
            size_t i5 = (size_t)(sQ[s+5]*K_ + sR[s+5]) * VD_ + j;
            e5 = elut[i5]; a5 = alut[i5];
        }
        if (tid < M_ && s+4 < S_) wcC = clut[(size_t)sQ[s+4] * M_ + tid];
        if (tid < M_ && s+5 < S_) wcD = clut[(size_t)sQ[s+5] * M_ + tid];

        // step s (rpart buffer 0)
        {
            const float* w = &wsh[s & 3][m0];
            float r = 0.f;
#pragma unroll
            for (int m = 0; m < 25; ++m) {
                float wm = w[m];
                r = fmaf(wm, mem[m], r);
                float t = fmaf(-e0, mem[m], a0);
                mem[m] = fmaf(wm, t, mem[m]);
            }
            if (g == 1 && act) rpart[0][j] = r;
            __syncthreads();
            if (g == 0 && act) rb[s * VD_ + j] = r + rpart[0][j];
        }
        // step s+1 (rpart buffer 1)
        {
            const float* w = &wsh[(s+1) & 3][m0];
            float r = 0.f;
#pragma unroll
            for (int m = 0; m < 25; ++m) {
                float wm = w[m];
                r = fmaf(wm, mem[m], r);
                float t = fmaf(-e1, mem[m], a1);
                mem[m] = fmaf(wm, t, mem[m]);
            }
            if (g == 1 && act) rpart[1][j] = r;
            __syncthreads();
            if (g == 0 && act) rb[(s+1) * VD_ + j] = r + rpart[1][j];
        }
        e0 = e2; a0 = a2; e1 = e3; a1 = a3;
        e2 = e4; a2 = a4; e3 = e5; a3 = a5;
        wcA = wcC; wcB = wcD;
    }
}

// ---------------------------------------------------------------------------
// k4: summary GEMM + fused head (unchanged).
// ---------------------------------------------------------------------------
#define BT4 80
#define KA  250
#define BK4 25
__global__ __launch_bounds__(256) void k4_head(
    const int* __restrict__ q_data, const float* __restrict__ q_tab,
    const float* __restrict__ reads,
    const float* __restrict__ W_sum, const float* __restrict__ b_sum,
    const float* __restrict__ W_ab, const float* __restrict__ b_ab,
    const float* __restrict__ W_th, const float* __restrict__ b_th,
    const float* __restrict__ W_disc, const float* __restrict__ b_disc,
    float* __restrict__ out)
{
    __shared__ __align__(16) float sAt[BK4][84];
    __shared__ __align__(16) float sW[BK4][52];
    __shared__ __align__(16) float sSum[BT4][52];
    __shared__ int sQ[BT4];

    const int tid  = threadIdx.x;
    const int tok0 = blockIdx.x * BT4;

    const int ty = tid / 25;
    const int tx = tid % 25;
    const bool act = (tid < 250);
    const int t0 = ty * 8;

    if (tid < BT4) sQ[tid] = q_data[tok0 + tid];

    float acc[8][2];
#pragma unroll
    for (int i = 0; i < 8; ++i) { acc[i][0] = 0.f; acc[i][1] = 0.f; }

    for (int kt = 0; kt < KA; kt += BK4) {
        __syncthreads();
        for (int i = tid; i < BT4 * BK4; i += 256) {
            int t = i / BK4, kk = i % BK4;
            float v;
            if (kt < VD_) v = reads[(size_t)(tok0 + t) * VD_ + kt + kk];
            else          v = q_tab[(size_t)sQ[t] * KD_ + (kt - VD_) + kk];
            sAt[kk][t] = v;
        }
        for (int i = tid; i < BK4 * FD_; i += 256) {
            int kk = i / FD_, col = i % FD_;
            sW[kk][col] = W_sum[(size_t)(kt + kk) * FD_ + col];
        }
        __syncthreads();

        if (act) {
#pragma unroll 5
            for (int kk = 0; kk < BK4; ++kk) {
                float2 w = *(const float2*)&sW[kk][2 * tx];
                float4 a0 = *(const float4*)&sAt[kk][t0];
                float4 a1 = *(const float4*)&sAt[kk][t0 + 4];
                float av[8] = {a0.x, a0.y, a0.z, a0.w, a1.x, a1.y, a1.z, a1.w};
#pragma unroll
                for (int i = 0; i < 8; ++i) {
                    acc[i][0] += av[i] * w.x;
                    acc[i][1] += av[i] * w.y;
                }
            }
        }
    }

    if (act) {
        const float b0 = b_sum[2 * tx], b1 = b_sum[2 * tx + 1];
#pragma unroll
        for (int i = 0; i < 8; ++i) {
            sSum[t0 + i][2 * tx]     = tanhf(acc[i][0] + b0);
            sSum[t0 + i][2 * tx + 1] = tanhf(acc[i][1] + b1);
        }
    }
    __syncthreads();

    const int wv   = tid >> 6;
    const int lane = tid & 63;
    for (int lt = wv * 20; lt < wv * 20 + 20; ++lt) {
        const int tok = tok0 + lt;
        const float s  = (lane < FD_) ? sSum[lt][lane] : 0.0f;
        const int  qi  = sQ[lt];
        const float qv = (lane < KD_) ? q_tab[(size_t)qi * KD_ + lane] : 0.0f;

        float v_ab = (lane < FD_) ? s * W_ab[lane] : 0.0f;
        float v_d  = ((lane < FD_) ? s * W_disc[lane] : 0.0f)
                   + ((lane < KD_) ? qv * W_disc[FD_ + lane] : 0.0f);
        float v_t0 = (lane < KD_) ? qv * W_th[lane * 3 + 0] : 0.0f;
        float v_t1 = (lane < KD_) ? qv * W_th[lane * 3 + 1] : 0.0f;
        float v_t2 = (lane < KD_) ? qv * W_th[lane * 3 + 2] : 0.0f;

#pragma unroll
        for (int off = 32; off; off >>= 1) {
            v_ab += __shfl_xor(v_ab, off);
            v_d  += __shfl_xor(v_d,  off);
            v_t0 += __shfl_xor(v_t0, off);
            v_t1 += __shfl_xor(v_t1, off);
            v_t2 += __shfl_xor(v_t2, off);
        }

        if (lane == 0) {
            float theta = 3.0f * (v_ab + b_ab[0]);
            float xd = v_d + b_disc[0];
            float alpha = fmaxf(xd, 0.0f) + log1pf(expf(-fabsf(xd)));
            float beta0 = tanhf(v_t0 + b_th[0]);
            float beta1 = tanhf(v_t1 + b_th[1]);
            float beta2 = tanhf(v_t2 + b_th[2]);
            float c1 = alpha * (theta - beta0);
            float c2 = c1 + alpha * (theta - beta1);
            float c3 = c2 + alpha * (theta - beta2);
            float mx = fmaxf(fmaxf(0.0f, c1), fmaxf(c2, c3));
            float e0 = expf(0.0f - mx), e1 = expf(c1 - mx),
                  e2 = expf(c2 - mx), e3 = expf(c3 - mx);
            float s4 = e0 + e1 + e2 + e3;
            float4 o = make_float4(e0 / s4, e1 / s4, e2 / s4, e3 / s4);
            *(float4*)&out[(size_t)tok * 4] = o;
        }
    }
}

// ---------------------------------------------------------------------------
extern "C" void kernel_launch(void* const* d_in, const int* in_sizes, int n_in,
                              void* d_out, int out_size, void* d_ws, size_t ws_size,
                              hipStream_t stream) {
    const int*   q_data   = (const int*)  d_in[0];
    const int*   r_data   = (const int*)  d_in[1];
    const float* q_tab    = (const float*)d_in[2];
    const float* key_mem  = (const float*)d_in[3];
    const float* init_mem = (const float*)d_in[4];
    const float* W_qk     = (const float*)d_in[5];
    const float* b_qk     = (const float*)d_in[6];
    const float* W_v3     = (const float*)d_in[7];
    const float* b_v      = (const float*)d_in[8];
    const float* W_e      = (const float*)d_in[9];
    const float* b_e      = (const float*)d_in[10];
    const float* W_a      = (const float*)d_in[11];
    const float* b_a      = (const float*)d_in[12];
    const float* W_sum    = (const float*)d_in[13];
    const float* b_sum    = (const float*)d_in[14];
    const float* W_ab     = (const float*)d_in[15];
    const float* b_ab     = (const float*)d_in[16];
    const float* W_th     = (const float*)d_in[17];
    const float* b_th     = (const float*)d_in[18];
    const float* W_disc   = (const float*)d_in[19];
    const float* b_disc   = (const float*)d_in[20];

    float* ws    = (float*)d_ws;
    float* reads = ws;                                   // T*VD = 10.24M floats
    float* clut  = reads + (size_t)T_ * VD_;             // 401*50
    float* elut  = clut + (size_t)(NQ_ + 1) * M_;        // 1604*200
    float* alut  = elut + (size_t)NE_ * VD_;             // 1604*200
    // total ~10.9M floats = 43.6 MB

    kA1_corrlut<<<(NQ_ + 4) / 4, 256, 0, stream>>>(q_tab, key_mem, W_qk, b_qk, clut);
    kA2_ealut<<<NQ_ + 1, 256, 0, stream>>>(W_v3, b_v, W_e, b_e, W_a, b_a, elut, alut);
    kB_scan<<<B_, 512, 0, stream>>>(q_data, r_data, init_mem, clut, elut, alut, reads);
    k4_head<<<T_ / BT4, 256, 0, stream>>>(q_data, q_tab, reads,
                                          W_sum, b_sum, W_ab, b_ab,
                                          W_th, b_th, W_disc, b_disc,
                                          (float*)d_out);
}

// Round 9
// 222.483 us; speedup vs baseline: 1.9406x; 1.1371x over previous
//
#include <hip/hip_runtime.h>
#include <math.h>

#define B_   256
#define S_   200
#define NQ_  400
#define K_   4
#define M_   50
#define KD_  50
#define VD_  200
#define FD_  50
#define T_   (B_*S_)   // 51200 tokens
#define NE_  ((NQ_+1)*K_)   // 1604 distinct (q,r) rows

// ---------------------------------------------------------------------------
// kA1: corr LUT [401][50]. corr is a pure function of q.
// ---------------------------------------------------------------------------
__global__ __launch_bounds__(256) void kA1_corrlut(
    const float* __restrict__ q_tab, const float* __restrict__ key_mem,
    const float* __restrict__ W_qk, const float* __restrict__ b_qk,
    float* __restrict__ clut)
{
    const int wave = threadIdx.x >> 6;
    const int lane = threadIdx.x & 63;
    int qi = blockIdx.x * 4 + wave;
    const bool valid = (qi <= NQ_);
    if (qi > NQ_) qi = NQ_;

    __shared__ float sqk[4][KD_];
    const float* qe = q_tab + (size_t)qi * KD_;
    if (lane < KD_) {
        float acc = b_qk[lane];
#pragma unroll 10
        for (int k = 0; k < KD_; ++k)
            acc += qe[k] * W_qk[k * KD_ + lane];
        sqk[wave][lane] = tanhf(acc);
    }
    __syncthreads();

    float c = -INFINITY;
    if (lane < M_) {
        float acc = 0.0f;
#pragma unroll 10
        for (int k = 0; k < KD_; ++k)
            acc += sqk[wave][k] * key_mem[lane * KD_ + k];
        c = acc;
    }
    float mx = c;
#pragma unroll
    for (int off = 32; off; off >>= 1) mx = fmaxf(mx, __shfl_xor(mx, off));
    float e = (lane < M_) ? expf(c - mx) : 0.0f;
    float sm = e;
#pragma unroll
    for (int off = 32; off; off >>= 1) sm += __shfl_xor(sm, off);
    if (valid && lane < M_) clut[(size_t)qi * M_ + lane] = e / sm;
}

// ---------------------------------------------------------------------------
// kA2: erase/add LUT [1604][200]. One block per q, all 4 r-variants.
// ---------------------------------------------------------------------------
__global__ __launch_bounds__(256) void kA2_ealut(
    const float* __restrict__ W_v3, const float* __restrict__ b_v,
    const float* __restrict__ W_e, const float* __restrict__ b_e,
    const float* __restrict__ W_a, const float* __restrict__ b_a,
    float* __restrict__ elut, float* __restrict__ alut)
{
    __shared__ __align__(16) float sV[VD_][4];   // [k][r]
    const int qi  = blockIdx.x;                  // 0..400
    const int tid = threadIdx.x;
    const float qm = (qi > 0) ? 1.0f : 0.0f;
    int idx = qi - 1;
    if (idx < 0) idx = 0;

    float wc[4][4];
#pragma unroll
    for (int r = 0; r < 4; ++r)
#pragma unroll
        for (int k = 0; k < 4; ++k) {
            float dist = fabsf((float)k - (float)r) / (float)(K_ - 1);
            float w = 1.0f - dist;
            wc[r][k] = (w > 0.0f) ? w : 0.0f;
        }

    if (tid < VD_) {
        float w3[4];
#pragma unroll
        for (int k = 0; k < 4; ++k)
            w3[k] = W_v3[((size_t)k * NQ_ + idx) * VD_ + tid];
        float bv = b_v[tid];
#pragma unroll
        for (int r = 0; r < 4; ++r) {
            float s = wc[r][0]*w3[0] + wc[r][1]*w3[1] + wc[r][2]*w3[2] + wc[r][3]*w3[3];
            sV[tid][r] = bv + qm * s;
        }
    }
    __syncthreads();

    if (tid < VD_) {
        const int c = tid;
        float accE[4] = {0.f,0.f,0.f,0.f}, accA[4] = {0.f,0.f,0.f,0.f};
#pragma unroll 4
        for (int k = 0; k < VD_; ++k) {
            float we = W_e[(size_t)k * VD_ + c];
            float wa = W_a[(size_t)k * VD_ + c];
            float4 v = *(const float4*)&sV[k][0];
            float vv[4] = {v.x, v.y, v.z, v.w};
#pragma unroll
            for (int r = 0; r < 4; ++r) {
                accE[r] = fmaf(vv[r], we, accE[r]);
                accA[r] = fmaf(vv[r], wa, accA[r]);
            }
        }
        const float be = b_e[c], ba = b_a[c];
#pragma unroll
        for (int r = 0; r < 4; ++r) {
            const size_t row = (size_t)qi * K_ + r;
            elut[row * VD_ + c] = 1.0f / (1.0f + expf(-(accE[r] + be)));
            alut[row * VD_ + c] = tanhf(accA[r] + ba);
        }
    }
}

// ---------------------------------------------------------------------------
// kB v6: scan with ZERO barriers in the step loop.
// The per-step barrier was fatal: hipcc drains vmcnt(0) before every
// s_barrier, so each step waited for that iteration's prefetch loads.
// Now: 256 threads, thread j owns all M=50 slots of column j. The entire
// corr sequence (S x M = 40 KB) is staged into LDS ONCE (one barrier),
// then the loop reads it as uniform broadcasts; e/a use a 4-deep register
// prefetch whose L2 gathers genuinely stay in flight.
// ---------------------------------------------------------------------------
__global__ __launch_bounds__(256) void kB_scan(
    const int* __restrict__ q_data, const int* __restrict__ r_data,
    const float* __restrict__ init_mem, const float* __restrict__ clut,
    const float* __restrict__ elut, const float* __restrict__ alut,
    float* __restrict__ reads)
{
    const int b   = blockIdx.x;
    const int tid = threadIdx.x;
    const int j   = tid;
    const bool act = (j < VD_);

    __shared__ int   sQ[S_], sR[S_];
    __shared__ float wall[S_][M_];   // 40 KB: all corr rows for this batch

    for (int i = tid; i < S_; i += 256) {
        sQ[i] = q_data[b * S_ + i];
        sR[i] = r_data[b * S_ + i];
    }
    __syncthreads();   // sQ visible for wall staging

    for (int i = tid; i < S_ * M_; i += 256) {
        int row = i / M_, col = i - row * M_;
        wall[row][col] = clut[(size_t)sQ[row] * M_ + col];
    }

    float mem[M_];
    if (act) {
#pragma unroll
        for (int m = 0; m < M_; ++m) mem[m] = init_mem[m * VD_ + j];
    }
    __syncthreads();   // wall visible — LAST barrier

    float* rb = reads + (size_t)b * S_ * VD_;

    // 4-deep e/a register pipeline
    float e0=0,a0=0,e1=0,a1=0,e2=0,a2=0,e3=0,a3=0;
    if (act) {
        size_t i0 = (size_t)(sQ[0]*K_ + sR[0]) * VD_ + j;
        size_t i1 = (size_t)(sQ[1]*K_ + sR[1]) * VD_ + j;
        size_t i2 = (size_t)(sQ[2]*K_ + sR[2]) * VD_ + j;
        size_t i3 = (size_t)(sQ[3]*K_ + sR[3]) * VD_ + j;
        e0 = elut[i0]; a0 = alut[i0];
        e1 = elut[i1]; a1 = alut[i1];
        e2 = elut[i2]; a2 = alut[i2];
        e3 = elut[i3]; a3 = alut[i3];
    }

    for (int s = 0; s < S_; s += 2) {
        // prefetch rows s+4, s+5 (consumed 2 iterations later; no barrier
        // ever forces these to drain)
        float e4=0,a4=0,e5=0,a5=0;
        if (act && s+4 < S_) {
            size_t i4 = (size_t)(sQ[s+4]*K_ + sR[s+4]) * VD_ + j;
            e4 = elut[i4]; a4 = alut[i4];
        }
        if (act && s+5 < S_) {
            size_t i5 = (size_t)(sQ[s+5]*K_ + sR[s+5]) * VD_ + j;
            e5 = elut[i5]; a5 = alut[i5];
        }

        // step s
        {
            const float* w = &wall[s][0];
            float ra = 0.f, rc = 0.f;
#pragma unroll
            for (int m = 0; m < M_; m += 2) {
                float w0 = w[m], w1 = w[m+1];
                ra = fmaf(w0, mem[m], ra);
                float t0 = fmaf(-e0, mem[m], a0);
                mem[m] = fmaf(w0, t0, mem[m]);
                rc = fmaf(w1, mem[m+1], rc);
                float t1 = fmaf(-e0, mem[m+1], a0);
                mem[m+1] = fmaf(w1, t1, mem[m+1]);
            }
            if (act) rb[s * VD_ + j] = ra + rc;
        }
        // step s+1
        {
            const float* w = &wall[s+1][0];
            float ra = 0.f, rc = 0.f;
#pragma unroll
            for (int m = 0; m < M_; m += 2) {
                float w0 = w[m], w1 = w[m+1];
                ra = fmaf(w0, mem[m], ra);
                float t0 = fmaf(-e1, mem[m], a1);
                mem[m] = fmaf(w0, t0, mem[m]);
                rc = fmaf(w1, mem[m+1], rc);
                float t1 = fmaf(-e1, mem[m+1], a1);
                mem[m+1] = fmaf(w1, t1, mem[m+1]);
            }
            if (act) rb[(s+1) * VD_ + j] = ra + rc;
        }
        e0 = e2; a0 = a2; e1 = e3; a1 = a3;
        e2 = e4; a2 = a4; e3 = e5; a3 = a5;
    }
}

// ---------------------------------------------------------------------------
// k4: summary GEMM + fused head (unchanged).
// ---------------------------------------------------------------------------
#define BT4 80
#define KA  250
#define BK4 25
__global__ __launch_bounds__(256) void k4_head(
    const int* __restrict__ q_data, const float* __restrict__ q_tab,
    const float* __restrict__ reads,
    const float* __restrict__ W_sum, const float* __restrict__ b_sum,
    const float* __restrict__ W_ab, const float* __restrict__ b_ab,
    const float* __restrict__ W_th, const float* __restrict__ b_th,
    const float* __restrict__ W_disc, const float* __restrict__ b_disc,
    float* __restrict__ out)
{
    __shared__ __align__(16) float sAt[BK4][84];
    __shared__ __align__(16) float sW[BK4][52];
    __shared__ __align__(16) float sSum[BT4][52];
    __shared__ int sQ[BT4];

    const int tid  = threadIdx.x;
    const int tok0 = blockIdx.x * BT4;

    const int ty = tid / 25;
    const int tx = tid % 25;
    const bool act = (tid < 250);
    const int t0 = ty * 8;

    if (tid < BT4) sQ[tid] = q_data[tok0 + tid];

    float acc[8][2];
#pragma unroll
    for (int i = 0; i < 8; ++i) { acc[i][0] = 0.f; acc[i][1] = 0.f; }

    for (int kt = 0; kt < KA; kt += BK4) {
        __syncthreads();
        for (int i = tid; i < BT4 * BK4; i += 256) {
            int t = i / BK4, kk = i % BK4;
            float v;
            if (kt < VD_) v = reads[(size_t)(tok0 + t) * VD_ + kt + kk];
            else          v = q_tab[(size_t)sQ[t] * KD_ + (kt - VD_) + kk];
            sAt[kk][t] = v;
        }
        for (int i = tid; i < BK4 * FD_; i += 256) {
            int kk = i / FD_, col = i % FD_;
            sW[kk][col] = W_sum[(size_t)(kt + kk) * FD_ + col];
        }
        __syncthreads();

        if (act) {
#pragma unroll 5
            for (int kk = 0; kk < BK4; ++kk) {
                float2 w = *(const float2*)&sW[kk][2 * tx];
                float4 a0 = *(const float4*)&sAt[kk][t0];
                float4 a1 = *(const float4*)&sAt[kk][t0 + 4];
                float av[8] = {a0.x, a0.y, a0.z, a0.w, a1.x, a1.y, a1.z, a1.w};
#pragma unroll
                for (int i = 0; i < 8; ++i) {
                    acc[i][0] += av[i] * w.x;
                    acc[i][1] += av[i] * w.y;
                }
            }
        }
    }

    if (act) {
        const float b0 = b_sum[2 * tx], b1 = b_sum[2 * tx + 1];
#pragma unroll
        for (int i = 0; i < 8; ++i) {
            sSum[t0 + i][2 * tx]     = tanhf(acc[i][0] + b0);
            sSum[t0 + i][2 * tx + 1] = tanhf(acc[i][1] + b1);
        }
    }
    __syncthreads();

    const int wv   = tid >> 6;
    const int lane = tid & 63;
    for (int lt = wv * 20; lt < wv * 20 + 20; ++lt) {
        const int tok = tok0 + lt;
        const float s  = (lane < FD_) ? sSum[lt][lane] : 0.0f;
        const int  qi  = sQ[lt];
        const float qv = (lane < KD_) ? q_tab[(size_t)qi * KD_ + lane] : 0.0f;

        float v_ab = (lane < FD_) ? s * W_ab[lane] : 0.0f;
        float v_d  = ((lane < FD_) ? s * W_disc[lane] : 0.0f)
                   + ((lane < KD_) ? qv * W_disc[FD_ + lane] : 0.0f);
        float v_t0 = (lane < KD_) ? qv * W_th[lane * 3 + 0] : 0.0f;
        float v_t1 = (lane < KD_) ? qv * W_th[lane * 3 + 1] : 0.0f;
        float v_t2 = (lane < KD_) ? qv * W_th[lane * 3 + 2] : 0.0f;

#pragma unroll
        for (int off = 32; off; off >>= 1) {
            v_ab += __shfl_xor(v_ab, off);
            v_d  += __shfl_xor(v_d,  off);
            v_t0 += __shfl_xor(v_t0, off);
            v_t1 += __shfl_xor(v_t1, off);
            v_t2 += __shfl_xor(v_t2, off);
        }

        if (lane == 0) {
            float theta = 3.0f * (v_ab + b_ab[0]);
            float xd = v_d + b_disc[0];
            float alpha = fmaxf(xd, 0.0f) + log1pf(expf(-fabsf(xd)));
            float beta0 = tanhf(v_t0 + b_th[0]);
            float beta1 = tanhf(v_t1 + b_th[1]);
            float beta2 = tanhf(v_t2 + b_th[2]);
            float c1 = alpha * (theta - beta0);
            float c2 = c1 + alpha * (theta - beta1);
            float c3 = c2 + alpha * (theta - beta2);
            float mx = fmaxf(fmaxf(0.0f, c1), fmaxf(c2, c3));
            float e0 = expf(0.0f - mx), e1 = expf(c1 - mx),
                  e2 = expf(c2 - mx), e3 = expf(c3 - mx);
            float s4 = e0 + e1 + e2 + e3;
            float4 o = make_float4(e0 / s4, e1 / s4, e2 / s4, e3 / s4);
            *(float4*)&out[(size_t)tok * 4] = o;
        }
    }
}

// ---------------------------------------------------------------------------
extern "C" void kernel_launch(void* const* d_in, const int* in_sizes, int n_in,
                              void* d_out, int out_size, void* d_ws, size_t ws_size,
                              hipStream_t stream) {
    const int*   q_data   = (const int*)  d_in[0];
    const int*   r_data   = (const int*)  d_in[1];
    const float* q_tab    = (const float*)d_in[2];
    const float* key_mem  = (const float*)d_in[3];
    const float* init_mem = (const float*)d_in[4];
    const float* W_qk     = (const float*)d_in[5];
    const float* b_qk     = (const float*)d_in[6];
    const float* W_v3     = (const float*)d_in[7];
    const float* b_v      = (const float*)d_in[8];
    const float* W_e      = (const float*)d_in[9];
    const float* b_e      = (const float*)d_in[10];
    const float* W_a      = (const float*)d_in[11];
    const float* b_a      = (const float*)d_in[12];
    const float* W_sum    = (const float*)d_in[13];
    const float* b_sum    = (const float*)d_in[14];
    const float* W_ab     = (const float*)d_in[15];
    const float* b_ab     = (const float*)d_in[16];
    const float* W_th     = (const float*)d_in[17];
    const float* b_th     = (const float*)d_in[18];
    const float* W_disc   = (const float*)d_in[19];
    const float* b_disc   = (const float*)d_in[20];

    float* ws    = (float*)d_ws;
    float* reads = ws;                                   // T*VD = 10.24M floats
    float* clut  = reads + (size_t)T_ * VD_;             // 401*50
    float* elut  = clut + (size_t)(NQ_ + 1) * M_;        // 1604*200
    float* alut  = elut + (size_t)NE_ * VD_;             // 1604*200

    kA1_corrlut<<<(NQ_ + 4) / 4, 256, 0, stream>>>(q_tab, key_mem, W_qk, b_qk, clut);
    kA2_ealut<<<NQ_ + 1, 256, 0, stream>>>(W_v3, b_v, W_e, b_e, W_a, b_a, elut, alut);
    kB_scan<<<B_, 256, 0, stream>>>(q_data, r_data, init_mem, clut, elut, alut, reads);
    k4_head<<<T_ / BT4, 256, 0, stream>>>(q_data, q_tab, reads,
                                          W_sum, b_sum, W_ab, b_ab,
                                          W_th, b_th, W_disc, b_disc,
                                          (float*)d_out);
}

// Round 10
// 222.353 us; speedup vs baseline: 1.9418x; 1.0006x over previous
//
#include <hip/hip_runtime.h>
#include <math.h>

#define B_   256
#define S_   200
#define NQ_  400
#define K_   4
#define M_   50
#define KD_  50
#define VD_  200
#define FD_  50
#define T_   (B_*S_)   // 51200 tokens
#define NE_  ((NQ_+1)*K_)   // 1604 distinct (q,r) rows

// ---------------------------------------------------------------------------
// kA1: corr LUT [401][50]. corr is a pure function of q.
// ---------------------------------------------------------------------------
__global__ __launch_bounds__(256) void kA1_corrlut(
    const float* __restrict__ q_tab, const float* __restrict__ key_mem,
    const float* __restrict__ W_qk, const float* __restrict__ b_qk,
    float* __restrict__ clut)
{
    const int wave = threadIdx.x >> 6;
    const int lane = threadIdx.x & 63;
    int qi = blockIdx.x * 4 + wave;
    const bool valid = (qi <= NQ_);
    if (qi > NQ_) qi = NQ_;

    __shared__ float sqk[4][KD_];
    const float* qe = q_tab + (size_t)qi * KD_;
    if (lane < KD_) {
        float acc = b_qk[lane];
#pragma unroll 10
        for (int k = 0; k < KD_; ++k)
            acc += qe[k] * W_qk[k * KD_ + lane];
        sqk[wave][lane] = tanhf(acc);
    }
    __syncthreads();

    float c = -INFINITY;
    if (lane < M_) {
        float acc = 0.0f;
#pragma unroll 10
        for (int k = 0; k < KD_; ++k)
            acc += sqk[wave][k] * key_mem[lane * KD_ + k];
        c = acc;
    }
    float mx = c;
#pragma unroll
    for (int off = 32; off; off >>= 1) mx = fmaxf(mx, __shfl_xor(mx, off));
    float e = (lane < M_) ? expf(c - mx) : 0.0f;
    float sm = e;
#pragma unroll
    for (int off = 32; off; off >>= 1) sm += __shfl_xor(sm, off);
    if (valid && lane < M_) clut[(size_t)qi * M_ + lane] = e / sm;
}

// ---------------------------------------------------------------------------
// kA2: erase/add LUT [1604][200]. One block per q, all 4 r-variants.
// ---------------------------------------------------------------------------
__global__ __launch_bounds__(256) void kA2_ealut(
    const float* __restrict__ W_v3, const float* __restrict__ b_v,
    const float* __restrict__ W_e, const float* __restrict__ b_e,
    const float* __restrict__ W_a, const float* __restrict__ b_a,
    float* __restrict__ elut, float* __restrict__ alut)
{
    __shared__ __align__(16) float sV[VD_][4];   // [k][r]
    const int qi  = blockIdx.x;                  // 0..400
    const int tid = threadIdx.x;
    const float qm = (qi > 0) ? 1.0f : 0.0f;
    int idx = qi - 1;
    if (idx < 0) idx = 0;

    float wc[4][4];
#pragma unroll
    for (int r = 0; r < 4; ++r)
#pragma unroll
        for (int k = 0; k < 4; ++k) {
            float dist = fabsf((float)k - (float)r) / (float)(K_ - 1);
            float w = 1.0f - dist;
            wc[r][k] = (w > 0.0f) ? w : 0.0f;
        }

    if (tid < VD_) {
        float w3[4];
#pragma unroll
        for (int k = 0; k < 4; ++k)
            w3[k] = W_v3[((size_t)k * NQ_ + idx) * VD_ + tid];
        float bv = b_v[tid];
#pragma unroll
        for (int r = 0; r < 4; ++r) {
            float s = wc[r][0]*w3[0] + wc[r][1]*w3[1] + wc[r][2]*w3[2] + wc[r][3]*w3[3];
            sV[tid][r] = bv + qm * s;
        }
    }
    __syncthreads();

    if (tid < VD_) {
        const int c = tid;
        float accE[4] = {0.f,0.f,0.f,0.f}, accA[4] = {0.f,0.f,0.f,0.f};
#pragma unroll 4
        for (int k = 0; k < VD_; ++k) {
            float we = W_e[(size_t)k * VD_ + c];
            float wa = W_a[(size_t)k * VD_ + c];
            float4 v = *(const float4*)&sV[k][0];
            float vv[4] = {v.x, v.y, v.z, v.w};
#pragma unroll
            for (int r = 0; r < 4; ++r) {
                accE[r] = fmaf(vv[r], we, accE[r]);
                accA[r] = fmaf(vv[r], wa, accA[r]);
            }
        }
        const float be = b_e[c], ba = b_a[c];
#pragma unroll
        for (int r = 0; r < 4; ++r) {
            const size_t row = (size_t)qi * K_ + r;
            elut[row * VD_ + c] = 1.0f / (1.0f + expf(-(accE[r] + be)));
            alut[row * VD_ + c] = tanhf(accA[r] + ba);
        }
    }
}

// ---------------------------------------------------------------------------
// kB v7: barrier-free scan + register-prefetched corr rows.
// wall rows for steps s/s+1 live in wA/wB (25 x float2 regs, constant
// indices). Immediately after step s consumes wA, ds_reads refill it with
// row s+2; the step-s+1 compute hides the LDS latency. VGPR ~190 is free:
// occupancy is grid-capped at 1 wave/SIMD regardless.
// ---------------------------------------------------------------------------
__global__ __launch_bounds__(256) void kB_scan(
    const int* __restrict__ q_data, const int* __restrict__ r_data,
    const float* __restrict__ init_mem, const float* __restrict__ clut,
    const float* __restrict__ elut, const float* __restrict__ alut,
    float* __restrict__ reads)
{
    const int b   = blockIdx.x;
    const int tid = threadIdx.x;
    const int j   = tid;
    const bool act = (j < VD_);

    __shared__ int   sQ[S_], sR[S_];
    __shared__ float wall[S_][M_];   // 40 KB: all corr rows for this batch

    for (int i = tid; i < S_; i += 256) {
        sQ[i] = q_data[b * S_ + i];
        sR[i] = r_data[b * S_ + i];
    }
    __syncthreads();   // sQ visible for wall staging

    for (int i = tid; i < S_ * M_; i += 256) {
        int row = i / M_, col = i - row * M_;
        wall[row][col] = clut[(size_t)sQ[row] * M_ + col];
    }

    float mem[M_];
    if (act) {
#pragma unroll
        for (int m = 0; m < M_; ++m) mem[m] = init_mem[m * VD_ + j];
    }
    __syncthreads();   // wall visible — LAST barrier

    float* rb = reads + (size_t)b * S_ * VD_;

    // 4-deep e/a register pipeline
    float e0=0,a0=0,e1=0,a1=0,e2=0,a2=0,e3=0,a3=0;
    if (act) {
        size_t i0 = (size_t)(sQ[0]*K_ + sR[0]) * VD_ + j;
        size_t i1 = (size_t)(sQ[1]*K_ + sR[1]) * VD_ + j;
        size_t i2 = (size_t)(sQ[2]*K_ + sR[2]) * VD_ + j;
        size_t i3 = (size_t)(sQ[3]*K_ + sR[3]) * VD_ + j;
        e0 = elut[i0]; a0 = alut[i0];
        e1 = elut[i1]; a1 = alut[i1];
        e2 = elut[i2]; a2 = alut[i2];
        e3 = elut[i3]; a3 = alut[i3];
    }

    // corr rows 0,1 in registers
    float2 wA[25], wB[25];
#pragma unroll
    for (int i = 0; i < 25; ++i) {
        wA[i] = *(const float2*)&wall[0][2*i];
        wB[i] = *(const float2*)&wall[1][2*i];
    }

    for (int s = 0; s < S_; s += 2) {
        // prefetch e/a rows s+4, s+5 (consumed 2 iterations later)
        float e4=0,a4=0,e5=0,a5=0;
        if (act && s+4 < S_) {
            size_t i4 = (size_t)(sQ[s+4]*K_ + sR[s+4]) * VD_ + j;
            e4 = elut[i4]; a4 = alut[i4];
        }
        if (act && s+5 < S_) {
            size_t i5 = (size_t)(sQ[s+5]*K_ + sR[s+5]) * VD_ + j;
            e5 = elut[i5]; a5 = alut[i5];
        }

        // step s (uses wA)
        {
            float ra = 0.f, rc = 0.f;
#pragma unroll
            for (int i = 0; i < 25; ++i) {
                const int m = 2*i;
                float w0 = wA[i].x, w1 = wA[i].y;
                ra = fmaf(w0, mem[m], ra);
                float t0 = fmaf(-e0, mem[m], a0);
                mem[m] = fmaf(w0, t0, mem[m]);
                rc = fmaf(w1, mem[m+1], rc);
                float t1 = fmaf(-e0, mem[m+1], a0);
                mem[m+1] = fmaf(w1, t1, mem[m+1]);
            }
            if (act) rb[s * VD_ + j] = ra + rc;
        }
        // refill wA <- row s+2 (latency hidden under step s+1 compute)
        {
            const int row = (s+2 < S_) ? s+2 : S_-1;
#pragma unroll
            for (int i = 0; i < 25; ++i) wA[i] = *(const float2*)&wall[row][2*i];
        }
        // step s+1 (uses wB)
        {
            float ra = 0.f, rc = 0.f;
#pragma unroll
            for (int i = 0; i < 25; ++i) {
                const int m = 2*i;
                float w0 = wB[i].x, w1 = wB[i].y;
                ra = fmaf(w0, mem[m], ra);
                float t0 = fmaf(-e1, mem[m], a1);
                mem[m] = fmaf(w0, t0, mem[m]);
                rc = fmaf(w1, mem[m+1], rc);
                float t1 = fmaf(-e1, mem[m+1], a1);
                mem[m+1] = fmaf(w1, t1, mem[m+1]);
            }
            if (act) rb[(s+1) * VD_ + j] = ra + rc;
        }
        // refill wB <- row s+3 (latency hidden under next iteration's step s)
        {
            const int row = (s+3 < S_) ? s+3 : S_-1;
#pragma unroll
            for (int i = 0; i < 25; ++i) wB[i] = *(const float2*)&wall[row][2*i];
        }
        e0 = e2; a0 = a2; e1 = e3; a1 = a3;
        e2 = e4; a2 = a4; e3 = e5; a3 = a5;
    }
}

// ---------------------------------------------------------------------------
// k4a: summary GEMM only. BT=40 -> 1280 blocks (5/CU, ~20 waves/CU).
// Thread (ty=tid/25, tx=tid%25): 4 tokens x 2 cols. Writes summary
// TRANSPOSED: summT[c][tok] = tanh(acc + b_sum[c]) for k4b's coalesced read.
// ---------------------------------------------------------------------------
#define BT4A 40
__global__ __launch_bounds__(256) void k4a_summary(
    const int* __restrict__ q_data, const float* __restrict__ q_tab,
    const float* __restrict__ reads,
    const float* __restrict__ W_sum, const float* __restrict__ b_sum,
    float* __restrict__ summT)
{
    __shared__ __align__(16) float sAt[25][44];   // [kk][t], pad 44
    __shared__ __align__(16) float sW[25][52];
    __shared__ int sQ[BT4A];

    const int tid  = threadIdx.x;
    const int tok0 = blockIdx.x * BT4A;
    const int ty = tid / 25;        // 0..9 -> token group of 4
    const int tx = tid % 25;        // col pair
    const bool act = (tid < 250);
    const int t0 = ty * 4;

    if (tid < BT4A) sQ[tid] = q_data[tok0 + tid];

    float acc[4][2];
#pragma unroll
    for (int i = 0; i < 4; ++i) { acc[i][0] = 0.f; acc[i][1] = 0.f; }

    for (int kt = 0; kt < 250; kt += 25) {
        __syncthreads();
        for (int i = tid; i < BT4A * 25; i += 256) {
            int t = i / 25, kk = i % 25;
            float v;
            if (kt < VD_) v = reads[(size_t)(tok0 + t) * VD_ + kt + kk];
            else          v = q_tab[(size_t)sQ[t] * KD_ + (kt - VD_) + kk];
            sAt[kk][t] = v;
        }
        for (int i = tid; i < 25 * FD_; i += 256) {
            int kk = i / FD_, col = i % FD_;
            sW[kk][col] = W_sum[(size_t)(kt + kk) * FD_ + col];
        }
        __syncthreads();

        if (act) {
#pragma unroll 5
            for (int kk = 0; kk < 25; ++kk) {
                float2 w = *(const float2*)&sW[kk][2 * tx];
                float4 a0 = *(const float4*)&sAt[kk][t0];
                float av[4] = {a0.x, a0.y, a0.z, a0.w};
#pragma unroll
                for (int i = 0; i < 4; ++i) {
                    acc[i][0] = fmaf(av[i], w.x, acc[i][0]);
                    acc[i][1] = fmaf(av[i], w.y, acc[i][1]);
                }
            }
        }
    }

    if (act) {
        const float b0 = b_sum[2 * tx], b1 = b_sum[2 * tx + 1];
#pragma unroll
        for (int i = 0; i < 4; ++i) {
            const size_t tok = tok0 + t0 + i;
            summT[(size_t)(2 * tx)     * T_ + tok] = tanhf(acc[i][0] + b0);
            summT[(size_t)(2 * tx + 1) * T_ + tok] = tanhf(acc[i][1] + b1);
        }
    }
}

// ---------------------------------------------------------------------------
// k4b: per-token head. One thread per token; summT reads coalesced; W
// vectors are wave-uniform (scalar loads); no shfl, no LDS.
// ---------------------------------------------------------------------------
__global__ __launch_bounds__(256) void k4b_head(
    const int* __restrict__ q_data, const float* __restrict__ q_tab,
    const float* __restrict__ summT,
    const float* __restrict__ W_ab, const float* __restrict__ b_ab,
    const float* __restrict__ W_th, const float* __restrict__ b_th,
    const float* __restrict__ W_disc, const float* __restrict__ b_disc,
    float* __restrict__ out)
{
    const int tok = blockIdx.x * 256 + threadIdx.x;
    const int q = q_data[tok];
    const float* qe = q_tab + (size_t)q * KD_;

    float v_ab = 0.f, v_d = 0.f, v_t0 = 0.f, v_t1 = 0.f, v_t2 = 0.f;
#pragma unroll 10
    for (int c = 0; c < FD_; ++c) {
        float s  = summT[(size_t)c * T_ + tok];
        float qv = qe[c];
        v_ab = fmaf(s,  W_ab[c],        v_ab);
        v_d  = fmaf(s,  W_disc[c],      v_d);
        v_d  = fmaf(qv, W_disc[FD_ + c], v_d);
        v_t0 = fmaf(qv, W_th[c * 3 + 0], v_t0);
        v_t1 = fmaf(qv, W_th[c * 3 + 1], v_t1);
        v_t2 = fmaf(qv, W_th[c * 3 + 2], v_t2);
    }

    float theta = 3.0f * (v_ab + b_ab[0]);
    float xd = v_d + b_disc[0];
    float alpha = fmaxf(xd, 0.0f) + log1pf(expf(-fabsf(xd)));
    float beta0 = tanhf(v_t0 + b_th[0]);
    float beta1 = tanhf(v_t1 + b_th[1]);
    float beta2 = tanhf(v_t2 + b_th[2]);
    float c1 = alpha * (theta - beta0);
    float c2 = c1 + alpha * (theta - beta1);
    float c3 = c2 + alpha * (theta - beta2);
    float mx = fmaxf(fmaxf(0.0f, c1), fmaxf(c2, c3));
    float e0 = expf(0.0f - mx), e1 = expf(c1 - mx),
          e2 = expf(c2 - mx), e3 = expf(c3 - mx);
    float s4 = e0 + e1 + e2 + e3;
    float4 o = make_float4(e0 / s4, e1 / s4, e2 / s4, e3 / s4);
    *(float4*)&out[(size_t)tok * 4] = o;
}

// ---------------------------------------------------------------------------
extern "C" void kernel_launch(void* const* d_in, const int* in_sizes, int n_in,
                              void* d_out, int out_size, void* d_ws, size_t ws_size,
                              hipStream_t stream) {
    const int*   q_data   = (const int*)  d_in[0];
    const int*   r_data   = (const int*)  d_in[1];
    const float* q_tab    = (const float*)d_in[2];
    const float* key_mem  = (const float*)d_in[3];
    const float* init_mem = (const float*)d_in[4];
    const float* W_qk     = (const float*)d_in[5];
    const float* b_qk     = (const float*)d_in[6];
    const float* W_v3     = (const float*)d_in[7];
    const float* b_v      = (const float*)d_in[8];
    const float* W_e      = (const float*)d_in[9];
    const float* b_e      = (const float*)d_in[10];
    const float* W_a      = (const float*)d_in[11];
    const float* b_a      = (const float*)d_in[12];
    const float* W_sum    = (const float*)d_in[13];
    const float* b_sum    = (const float*)d_in[14];
    const float* W_ab     = (const float*)d_in[15];
    const float* b_ab     = (const float*)d_in[16];
    const float* W_th     = (const float*)d_in[17];
    const float* b_th     = (const float*)d_in[18];
    const float* W_disc   = (const float*)d_in[19];
    const float* b_disc   = (const float*)d_in[20];

    float* ws    = (float*)d_ws;
    float* reads = ws;                                   // T*VD
    float* clut  = reads + (size_t)T_ * VD_;             // 401*50
    float* elut  = clut + (size_t)(NQ_ + 1) * M_;        // 1604*200
    float* alut  = elut + (size_t)NE_ * VD_;             // 1604*200
    float* summT = alut + (size_t)NE_ * VD_;             // 50*T = 2.56M
    // total ~13.5M floats = 54 MB

    kA1_corrlut<<<(NQ_ + 4) / 4, 256, 0, stream>>>(q_tab, key_mem, W_qk, b_qk, clut);
    kA2_ealut<<<NQ_ + 1, 256, 0, stream>>>(W_v3, b_v, W_e, b_e, W_a, b_a, elut, alut);
    kB_scan<<<B_, 256, 0, stream>>>(q_data, r_data, init_mem, clut, elut, alut, reads);
    k4a_summary<<<T_ / BT4A, 256, 0, stream>>>(q_data, q_tab, reads, W_sum, b_sum, summT);
    k4b_head<<<T_ / 256, 256, 0, stream>>>(q_data, q_tab, summT,
                                           W_ab, b_ab, W_th, b_th, W_disc, b_disc,
                                           (float*)d_out);
}

// Round 11
// 183.793 us; speedup vs baseline: 2.3492x; 1.2098x over previous
//
#include <hip/hip_runtime.h>
#include <math.h>

#define B_   256
#define S_   200
#define NQ_  400
#define K_   4
#define M_   50
#define KD_  50
#define VD_  200
#define FD_  50
#define T_   (B_*S_)   // 51200 tokens
#define NE_  ((NQ_+1)*K_)   // 1604 distinct (q,r) rows

// ---------------------------------------------------------------------------
// kA1: corr LUT [401][50]. corr is a pure function of q.
// ---------------------------------------------------------------------------
__global__ __launch_bounds__(256) void kA1_corrlut(
    const float* __restrict__ q_tab, const float* __restrict__ key_mem,
    const float* __restrict__ W_qk, const float* __restrict__ b_qk,
    float* __restrict__ clut)
{
    const int wave = threadIdx.x >> 6;
    const int lane = threadIdx.x & 63;
    int qi = blockIdx.x * 4 + wave;
    const bool valid = (qi <= NQ_);
    if (qi > NQ_) qi = NQ_;

    __shared__ float sqk[4][KD_];
    const float* qe = q_tab + (size_t)qi * KD_;
    if (lane < KD_) {
        float acc = b_qk[lane];
#pragma unroll 10
        for (int k = 0; k < KD_; ++k)
            acc += qe[k] * W_qk[k * KD_ + lane];
        sqk[wave][lane] = tanhf(acc);
    }
    __syncthreads();

    float c = -INFINITY;
    if (lane < M_) {
        float acc = 0.0f;
#pragma unroll 10
        for (int k = 0; k < KD_; ++k)
            acc += sqk[wave][k] * key_mem[lane * KD_ + k];
        c = acc;
    }
    float mx = c;
#pragma unroll
    for (int off = 32; off; off >>= 1) mx = fmaxf(mx, __shfl_xor(mx, off));
    float e = (lane < M_) ? expf(c - mx) : 0.0f;
    float sm = e;
#pragma unroll
    for (int off = 32; off; off >>= 1) sm += __shfl_xor(sm, off);
    if (valid && lane < M_) clut[(size_t)qi * M_ + lane] = e / sm;
}

// ---------------------------------------------------------------------------
// kA2: erase/add LUT [1604][200]. One block per q, all 4 r-variants.
// ---------------------------------------------------------------------------
__global__ __launch_bounds__(256) void kA2_ealut(
    const float* __restrict__ W_v3, const float* __restrict__ b_v,
    const float* __restrict__ W_e, const float* __restrict__ b_e,
    const float* __restrict__ W_a, const float* __restrict__ b_a,
    float* __restrict__ elut, float* __restrict__ alut)
{
    __shared__ __align__(16) float sV[VD_][4];   // [k][r]
    const int qi  = blockIdx.x;                  // 0..400
    const int tid = threadIdx.x;
    const float qm = (qi > 0) ? 1.0f : 0.0f;
    int idx = qi - 1;
    if (idx < 0) idx = 0;

    float wc[4][4];
#pragma unroll
    for (int r = 0; r < 4; ++r)
#pragma unroll
        for (int k = 0; k < 4; ++k) {
            float dist = fabsf((float)k - (float)r) / (float)(K_ - 1);
            float w = 1.0f - dist;
            wc[r][k] = (w > 0.0f) ? w : 0.0f;
        }

    if (tid < VD_) {
        float w3[4];
#pragma unroll
        for (int k = 0; k < 4; ++k)
            w3[k] = W_v3[((size_t)k * NQ_ + idx) * VD_ + tid];
        float bv = b_v[tid];
#pragma unroll
        for (int r = 0; r < 4; ++r) {
            float s = wc[r][0]*w3[0] + wc[r][1]*w3[1] + wc[r][2]*w3[2] + wc[r][3]*w3[3];
            sV[tid][r] = bv + qm * s;
        }
    }
    __syncthreads();

    if (tid < VD_) {
        const int c = tid;
        float accE[4] = {0.f,0.f,0.f,0.f}, accA[4] = {0.f,0.f,0.f,0.f};
#pragma unroll 4
        for (int k = 0; k < VD_; ++k) {
            float we = W_e[(size_t)k * VD_ + c];
            float wa = W_a[(size_t)k * VD_ + c];
            float4 v = *(const float4*)&sV[k][0];
            float vv[4] = {v.x, v.y, v.z, v.w};
#pragma unroll
            for (int r = 0; r < 4; ++r) {
                accE[r] = fmaf(vv[r], we, accE[r]);
                accA[r] = fmaf(vv[r], wa, accA[r]);
            }
        }
        const float be = b_e[c], ba = b_a[c];
#pragma unroll
        for (int r = 0; r < 4; ++r) {
            const size_t row = (size_t)qi * K_ + r;
            elut[row * VD_ + c] = 1.0f / (1.0f + expf(-(accE[r] + be)));
            alut[row * VD_ + c] = tanhf(accA[r] + ba);
        }
    }
}

// ---------------------------------------------------------------------------
// kB v8: barrier-free scan, M split across 2 INDEPENDENT groups.
// 512 threads: group g (tid>>8) owns mem slots g*25..g*25+24 of column
// j (tid&255). Each group stores its PARTIAL read vector to its own buffer
// (reads0/reads1); k4a sums them during staging. So: zero step-loop
// barriers, zero cross-group traffic, per-wave issue halved, and
// 2 waves/SIMD (vs 1) to hide ds_read/L2 latency.
// Loop body identical to the v6 form (in-loop LDS w reads — v7's explicit
// register refill regressed and was reverted).
// ---------------------------------------------------------------------------
__global__ __launch_bounds__(512) void kB_scan(
    const int* __restrict__ q_data, const int* __restrict__ r_data,
    const float* __restrict__ init_mem, const float* __restrict__ clut,
    const float* __restrict__ elut, const float* __restrict__ alut,
    float* __restrict__ reads0, float* __restrict__ reads1)
{
    const int b   = blockIdx.x;
    const int tid = threadIdx.x;
    const int j   = tid & 255;
    const int g   = tid >> 8;          // 0 or 1
    const bool act = (j < VD_);
    const int m0  = g * 25;

    __shared__ int   sQ[S_], sR[S_];
    __shared__ float wall[S_][M_];   // 40 KB: all corr rows for this batch

    for (int i = tid; i < S_; i += 512) {
        sQ[i] = q_data[b * S_ + i];
        sR[i] = r_data[b * S_ + i];
    }
    __syncthreads();   // sQ visible for wall staging

    for (int i = tid; i < S_ * M_; i += 512) {
        int row = i / M_, col = i - row * M_;
        wall[row][col] = clut[(size_t)sQ[row] * M_ + col];
    }

    float mem[25];
    if (act) {
#pragma unroll
        for (int m = 0; m < 25; ++m) mem[m] = init_mem[(m0 + m) * VD_ + j];
    }
    __syncthreads();   // wall visible — LAST barrier

    float* rb = (g == 0 ? reads0 : reads1) + (size_t)b * S_ * VD_;

    // 4-deep e/a register pipeline
    float e0=0,a0=0,e1=0,a1=0,e2=0,a2=0,e3=0,a3=0;
    if (act) {
        size_t i0 = (size_t)(sQ[0]*K_ + sR[0]) * VD_ + j;
        size_t i1 = (size_t)(sQ[1]*K_ + sR[1]) * VD_ + j;
        size_t i2 = (size_t)(sQ[2]*K_ + sR[2]) * VD_ + j;
        size_t i3 = (size_t)(sQ[3]*K_ + sR[3]) * VD_ + j;
        e0 = elut[i0]; a0 = alut[i0];
        e1 = elut[i1]; a1 = alut[i1];
        e2 = elut[i2]; a2 = alut[i2];
        e3 = elut[i3]; a3 = alut[i3];
    }

    for (int s = 0; s < S_; s += 2) {
        // prefetch e/a rows s+4, s+5 (consumed 2 iterations later)
        float e4=0,a4=0,e5=0,a5=0;
        if (act && s+4 < S_) {
            size_t i4 = (size_t)(sQ[s+4]*K_ + sR[s+4]) * VD_ + j;
            e4 = elut[i4]; a4 = alut[i4];
        }
        if (act && s+5 < S_) {
            size_t i5 = (size_t)(sQ[s+5]*K_ + sR[s+5]) * VD_ + j;
            e5 = elut[i5]; a5 = alut[i5];
        }

        // step s
        {
            const float* w = &wall[s][m0];
            float ra = 0.f, rc = 0.f;
#pragma unroll
            for (int m = 0; m < 25; m += 2) {
                float w0 = w[m];
                ra = fmaf(w0, mem[m], ra);
                float t0 = fmaf(-e0, mem[m], a0);
                mem[m] = fmaf(w0, t0, mem[m]);
                if (m + 1 < 25) {
                    float w1 = w[m+1];
                    rc = fmaf(w1, mem[m+1], rc);
                    float t1 = fmaf(-e0, mem[m+1], a0);
                    mem[m+1] = fmaf(w1, t1, mem[m+1]);
                }
            }
            if (act) rb[s * VD_ + j] = ra + rc;
        }
        // step s+1
        {
            const float* w = &wall[s+1][m0];
            float ra = 0.f, rc = 0.f;
#pragma unroll
            for (int m = 0; m < 25; m += 2) {
                float w0 = w[m];
                ra = fmaf(w0, mem[m], ra);
                float t0 = fmaf(-e1, mem[m], a1);
                mem[m] = fmaf(w0, t0, mem[m]);
                if (m + 1 < 25) {
                    float w1 = w[m+1];
                    rc = fmaf(w1, mem[m+1], rc);
                    float t1 = fmaf(-e1, mem[m+1], a1);
                    mem[m+1] = fmaf(w1, t1, mem[m+1]);
                }
            }
            if (act) rb[(s+1) * VD_ + j] = ra + rc;
        }
        e0 = e2; a0 = a2; e1 = e3; a1 = a3;
        e2 = e4; a2 = a4; e3 = e5; a3 = a5;
    }
}

// ---------------------------------------------------------------------------
// k4a: summary GEMM. Stages sAt = reads0 + reads1 (the two scan partials).
// BT=40 -> 1280 blocks. Writes summary transposed summT[c][tok].
// ---------------------------------------------------------------------------
#define BT4A 40
__global__ __launch_bounds__(256) void k4a_summary(
    const int* __restrict__ q_data, const float* __restrict__ q_tab,
    const float* __restrict__ reads0, const float* __restrict__ reads1,
    const float* __restrict__ W_sum, const float* __restrict__ b_sum,
    float* __restrict__ summT)
{
    __shared__ __align__(16) float sAt[25][44];   // [kk][t], pad 44
    __shared__ __align__(16) float sW[25][52];
    __shared__ int sQ[BT4A];

    const int tid  = threadIdx.x;
    const int tok0 = blockIdx.x * BT4A;
    const int ty = tid / 25;        // 0..9 -> token group of 4
    const int tx = tid % 25;        // col pair
    const bool act = (tid < 250);
    const int t0 = ty * 4;

    if (tid < BT4A) sQ[tid] = q_data[tok0 + tid];

    float acc[4][2];
#pragma unroll
    for (int i = 0; i < 4; ++i) { acc[i][0] = 0.f; acc[i][1] = 0.f; }

    for (int kt = 0; kt < 250; kt += 25) {
        __syncthreads();
        for (int i = tid; i < BT4A * 25; i += 256) {
            int t = i / 25, kk = i % 25;
            float v;
            if (kt < VD_) {
                size_t idx = (size_t)(tok0 + t) * VD_ + kt + kk;
                v = reads0[idx] + reads1[idx];
            } else {
                v = q_tab[(size_t)sQ[t] * KD_ + (kt - VD_) + kk];
            }
            sAt[kk][t] = v;
        }
        for (int i = tid; i < 25 * FD_; i += 256) {
            int kk = i / FD_, col = i % FD_;
            sW[kk][col] = W_sum[(size_t)(kt + kk) * FD_ + col];
        }
        __syncthreads();

        if (act) {
#pragma unroll 5
            for (int kk = 0; kk < 25; ++kk) {
                float2 w = *(const float2*)&sW[kk][2 * tx];
                float4 a0 = *(const float4*)&sAt[kk][t0];
                float av[4] = {a0.x, a0.y, a0.z, a0.w};
#pragma unroll
                for (int i = 0; i < 4; ++i) {
                    acc[i][0] = fmaf(av[i], w.x, acc[i][0]);
                    acc[i][1] = fmaf(av[i], w.y, acc[i][1]);
                }
            }
        }
    }

    if (act) {
        const float b0 = b_sum[2 * tx], b1 = b_sum[2 * tx + 1];
#pragma unroll
        for (int i = 0; i < 4; ++i) {
            const size_t tok = tok0 + t0 + i;
            summT[(size_t)(2 * tx)     * T_ + tok] = tanhf(acc[i][0] + b0);
            summT[(size_t)(2 * tx + 1) * T_ + tok] = tanhf(acc[i][1] + b1);
        }
    }
}

// ---------------------------------------------------------------------------
// k4b: per-token head. One thread per token; summT reads coalesced; W
// vectors wave-uniform; no shfl, no LDS.
// ---------------------------------------------------------------------------
__global__ __launch_bounds__(256) void k4b_head(
    const int* __restrict__ q_data, const float* __restrict__ q_tab,
    const float* __restrict__ summT,
    const float* __restrict__ W_ab, const float* __restrict__ b_ab,
    const float* __restrict__ W_th, const float* __restrict__ b_th,
    const float* __restrict__ W_disc, const float* __restrict__ b_disc,
    float* __restrict__ out)
{
    const int tok = blockIdx.x * 256 + threadIdx.x;
    const int q = q_data[tok];
    const float* qe = q_tab + (size_t)q * KD_;

    float v_ab = 0.f, v_d = 0.f, v_t0 = 0.f, v_t1 = 0.f, v_t2 = 0.f;
#pragma unroll 10
    for (int c = 0; c < FD_; ++c) {
        float s  = summT[(size_t)c * T_ + tok];
        float qv = qe[c];
        v_ab = fmaf(s,  W_ab[c],        v_ab);
        v_d  = fmaf(s,  W_disc[c],      v_d);
        v_d  = fmaf(qv, W_disc[FD_ + c], v_d);
        v_t0 = fmaf(qv, W_th[c * 3 + 0], v_t0);
        v_t1 = fmaf(qv, W_th[c * 3 + 1], v_t1);
        v_t2 = fmaf(qv, W_th[c * 3 + 2], v_t2);
    }

    float theta = 3.0f * (v_ab + b_ab[0]);
    float xd = v_d + b_disc[0];
    float alpha = fmaxf(xd, 0.0f) + log1pf(expf(-fabsf(xd)));
    float beta0 = tanhf(v_t0 + b_th[0]);
    float beta1 = tanhf(v_t1 + b_th[1]);
    float beta2 = tanhf(v_t2 + b_th[2]);
    float c1 = alpha * (theta - beta0);
    float c2 = c1 + alpha * (theta - beta1);
    float c3 = c2 + alpha * (theta - beta2);
    float mx = fmaxf(fmaxf(0.0f, c1), fmaxf(c2, c3));
    float e0 = expf(0.0f - mx), e1 = expf(c1 - mx),
          e2 = expf(c2 - mx), e3 = expf(c3 - mx);
    float s4 = e0 + e1 + e2 + e3;
    float4 o = make_float4(e0 / s4, e1 / s4, e2 / s4, e3 / s4);
    *(float4*)&out[(size_t)tok * 4] = o;
}

// ---------------------------------------------------------------------------
extern "C" void kernel_launch(void* const* d_in, const int* in_sizes, int n_in,
                              void* d_out, int out_size, void* d_ws, size_t ws_size,
                              hipStream_t stream) {
    const int*   q_data   = (const int*)  d_in[0];
    const int*   r_data   = (const int*)  d_in[1];
    const float* q_tab    = (const float*)d_in[2];
    const float* key_mem  = (const float*)d_in[3];
    const float* init_mem = (const float*)d_in[4];
    const float* W_qk     = (const float*)d_in[5];
    const float* b_qk     = (const float*)d_in[6];
    const float* W_v3     = (const float*)d_in[7];
    const float* b_v      = (const float*)d_in[8];
    const float* W_e      = (const float*)d_in[9];
    const float* b_e      = (const float*)d_in[10];
    const float* W_a      = (const float*)d_in[11];
    const float* b_a      = (const float*)d_in[12];
    const float* W_sum    = (const float*)d_in[13];
    const float* b_sum    = (const float*)d_in[14];
    const float* W_ab     = (const float*)d_in[15];
    const float* b_ab     = (const float*)d_in[16];
    const float* W_th     = (const float*)d_in[17];
    const float* b_th     = (const float*)d_in[18];
    const float* W_disc   = (const float*)d_in[19];
    const float* b_disc   = (const float*)d_in[20];

    float* ws     = (float*)d_ws;
    float* reads0 = ws;                                   // T*VD
    float* reads1 = reads0 + (size_t)T_ * VD_;            // T*VD
    float* clut   = reads1 + (size_t)T_ * VD_;            // 401*50
    float* elut   = clut + (size_t)(NQ_ + 1) * M_;        // 1604*200
    float* alut   = elut + (size_t)NE_ * VD_;             // 1604*200
    float* summT  = alut + (size_t)NE_ * VD_;             // 50*T
    // total ~23.7M floats = 95 MB

    kA1_corrlut<<<(NQ_ + 4) / 4, 256, 0, stream>>>(q_tab, key_mem, W_qk, b_qk, clut);
    kA2_ealut<<<NQ_ + 1, 256, 0, stream>>>(W_v3, b_v, W_e, b_e, W_a, b_a, elut, alut);
    kB_scan<<<B_, 512, 0, stream>>>(q_data, r_data, init_mem, clut, elut, alut,
                                    reads0, reads1);
    k4a_summary<<<T_ / BT4A, 256, 0, stream>>>(q_data, q_tab, reads0, reads1,
                                               W_sum, b_sum, summT);
    k4b_head<<<T_ / 256, 256, 0, stream>>>(q_data, q_tab, summT,
                                           W_ab, b_ab, W_th, b_th, W_disc, b_disc,
                                           (float*)d_out);
}